// Round 10
// baseline (608.539 us; speedup 1.0000x reference)
//
#include <hip/hip_runtime.h>
#include <math.h>

// Problem constants (match reference)
constexpr int NB = 32, NM = 64, NK = 8400, NC = 80, NT = 15;
constexpr int NQ = 4, KQ = 2100;       // k split into 4 quarters of 2100
constexpr float FEPS = 1e-7f;

typedef float f32x4 __attribute__((ext_vector_type(4)));   // NT-store compatible

// Output layout: [tso | tgt_bboxes | assign | overlaps | fg], all float32
constexpr size_t OUT_TSO = 0;
constexpr size_t OUT_TGT = (size_t)NB * NK * NC;            // 21504000
constexpr size_t OUT_ASN = OUT_TGT + (size_t)NB * NK * 4;   // 22579200
constexpr size_t OUT_OVL = OUT_ASN + (size_t)NB * NM * NK;  // 39782400
constexpr size_t OUT_FG  = OUT_OVL + (size_t)NB * NM * NK;  // 56985600

constexpr int NCOMP = NB * NM * NQ;    // 8192 compute blocks
constexpr int NFILL = 2048;            // fill blocks (every 5th block)
constexpr int N4A  = (int)(OUT_TGT / 4);              // tso region, f32x4 count
constexpr int N4B  = (int)((OUT_OVL - OUT_ASN) / 4);  // assign region
constexpr int ASN4 = (int)(OUT_ASN / 4);

// ---------------------------------------------------------------------------
// kZ: workspace init (mikey=0, fg0=0, done=0, flag=0). Must precede kAF.
// ---------------------------------------------------------------------------
__global__ __launch_bounds__(256) void kZ(unsigned long long* __restrict__ mikey,
                                          int* __restrict__ fg0,
                                          int* __restrict__ done,
                                          int* __restrict__ flag)
{
  const int n = NB * NK;
  const int tid = blockIdx.x * 256 + threadIdx.x;
  for (int i = tid; i < n; i += gridDim.x * 256) { mikey[i] = 0ULL; fg0[i] = 0; }
  if (tid < NB * NM) done[tid] = 0;
  if (tid == 0) *flag = 0;
}

// ---------------------------------------------------------------------------
// kAF: 10240 blocks, role-specialized (every 5th = fill, rest = compute).
//  fill   : streaming NT zero of tso+assign (155 MB over 2048 blocks)
//  compute: one block per (b,m,quarter):
//    pass 1: zero LDS ov tile + point-in-box -> ushort positive list
//    pass 2: CIoU on positives -> s_ov, mi atomicMax key, packed am keys
//    flush : dense f32x4 NT overlaps write from s_ov
//    tail  : per-quarter top-15 -> candk; LAST quarter block (done counter +
//            threadfence) merges 4x15 -> tki/tkv/ovmaxp + fg0/flag atomics
// ---------------------------------------------------------------------------
__global__ __launch_bounds__(256) void kAF(
    const float* __restrict__ points, const float* __restrict__ gt_bboxes,
    const int* __restrict__ gt_labels, const float* __restrict__ pred_bboxes,
    const float* __restrict__ pred_scores, const int* __restrict__ gt_mask,
    float* __restrict__ out, unsigned long long* __restrict__ candk,
    float* __restrict__ ovmaxq, float* __restrict__ ovmaxp,
    int* __restrict__ tki, float* __restrict__ tkv,
    unsigned long long* __restrict__ mikey, int* __restrict__ done,
    int* __restrict__ fg0, int* __restrict__ flag)
{
  __shared__ __align__(16) float s_ov[KQ];       // 8.4 KB dense overlaps tile
  __shared__ unsigned short s_pos[KQ];           // 4.2 KB positive local-idx list
  __shared__ unsigned long long s_key[KQ];       // 16.8 KB packed am candidates
  __shared__ int   s_np, s_cnt;
  __shared__ float s_m[4];

  const int bx = blockIdx.x;
  const int t  = threadIdx.x;

  // ---- fill role: every 5th block streams zeros into tso+assign ----
  if ((bx % 5) == 4) {
    const int fidx = bx / 5;
    f32x4* o4 = (f32x4*)out;
    const f32x4 z = {0.f, 0.f, 0.f, 0.f};
    for (int i = fidx * 256 + t; i < N4A + N4B; i += NFILL * 256) {
      const int a = (i < N4A) ? i : (i - N4A + ASN4);
      __builtin_nontemporal_store(z, &o4[a]);
    }
    return;
  }

  // ---- compute role ----
  const int cidx = bx - (bx + 1) / 5;            // 0..8191
  const int bm = cidx >> 2;                      // 4 quarter blocks adjacent
  const int q  = cidx & 3;
  const int b  = bm >> 6;
  const int m  = bm & 63;
  const int wid = t >> 6, lane = t & 63;
  const int kbeg = q * KQ;

  unsigned long long* ck = candk + (size_t)(bm * NQ + q) * NT;
  float* ovl_out = out + OUT_OVL + (size_t)bm * NK;
  f32x4* ov4 = (f32x4*)(ovl_out + kbeg);

  const int maskv = gt_mask[bm];
  if (!maskv) {
    const f32x4 z = {0.f, 0.f, 0.f, 0.f};
    for (int idx = t; idx < KQ / 4; idx += 256)
      __builtin_nontemporal_store(z, &ov4[idx]);
    if (t == 0) ovmaxq[bm * NQ + q] = 0.f;
    if (wid != 0) return;
    if (lane < NT) ck[lane] = 0ULL;
  } else {
    if (t == 0) { s_np = 0; s_cnt = 0; }
    __syncthreads();

    const float4 g = *(const float4*)(gt_bboxes + (size_t)bm * 4);
    const int   label = gt_labels[bm];
    const float2* pts = (const float2*)points;

    // pass 1: zero ov tile + point-in-box (diff.max(-1)<1e-6, exact f32 subs)
    #pragma unroll
    for (int j = 0; j < 9; ++j) {
      const int idx = j * 256 + t;
      if (idx < KQ) {
        s_ov[idx] = 0.f;
        const int k = kbeg + idx;
        float2 p = pts[k];
        float dmax = fmaxf(fmaxf(g.x - p.x, g.y - p.y),
                           fmaxf(p.x - g.z, p.y - g.w));
        if (dmax < 1e-6f) {
          int e = atomicAdd(&s_np, 1);
          s_pos[e] = (unsigned short)idx;
        }
      }
    }
    __syncthreads();
    const int np = s_np;

    const float4* pb = (const float4*)(pred_bboxes + (size_t)b * NK * 4);
    const float*  ps = pred_scores + (size_t)b * NK * NC;
    unsigned long long* mk = mikey + (size_t)b * NK;

    const float w1 = g.z - g.x, h1 = g.w - g.y;
    const float at1 = atanf(w1 / (h1 + FEPS));
    const float area1 = w1 * h1;
    const float CV = (float)(4.0 / (M_PI * M_PI));
    const float ONE_EPS = (float)(1.0 + 1e-7);

    float lmax = 0.f;
    for (int e = t; e < np; e += 256) {
      const int k = kbeg + s_pos[e];
      float4 qb = pb[k];
      float w2 = qb.z - qb.x, h2 = qb.w - qb.y;
      float iw = fmaxf(fminf(g.z, qb.z) - fmaxf(g.x, qb.x), 0.f);
      float ih = fmaxf(fminf(g.w, qb.w) - fmaxf(g.y, qb.y), 0.f);
      float inter = iw * ih;
      float uni = area1 + w2 * h2 - inter + FEPS;
      float iou = inter / uni;
      float cw = fmaxf(g.z, qb.z) - fminf(g.x, qb.x);
      float ch = fmaxf(g.w, qb.w) - fminf(g.y, qb.y);
      float c2 = cw * cw + ch * ch + FEPS;
      float ex = qb.x + qb.z - g.x - g.z;
      float ey = qb.y + qb.w - g.y - g.w;
      float rho2 = (ex * ex + ey * ey) * 0.25f;
      float dat = atanf(w2 / (h2 + FEPS)) - at1;
      float v = CV * dat * dat;
      float alpha = v / (v - iou + ONE_EPS);
      float ciou = iou - (rho2 / c2 + alpha * v);
      float ov = fmaxf(ciou, 0.f);
      if (ov > 0.f) {
        s_ov[k - kbeg] = ov;
        unsigned long long key =
            ((unsigned long long)__float_as_uint(ov) << 32) |
            (unsigned long long)(NM - 1 - m);           // value desc, first-m tie
        atomicMax(&mk[k], key);
        lmax = fmaxf(lmax, ov);
        float ts = ps[(size_t)k * NC + label];
        float o2 = ov * ov;
        float am = ts * (o2 * o2 * o2);                 // ts**1 * ov**6
        if (am > 1e-9f) {                               // below cutoff never selected
          int p2 = atomicAdd(&s_cnt, 1);
          s_key[p2] = ((unsigned long long)__float_as_uint(am) << 32) |
                      (unsigned long long)(0xFFFFFFFFu - (unsigned)k);
        }
      }
    }

    // partial row-max of overlaps
    float mv = lmax;
    #pragma unroll
    for (int d = 1; d < 64; d <<= 1) mv = fmaxf(mv, __shfl_xor(mv, d));
    if (lane == 0) s_m[wid] = mv;
    __syncthreads();   // finalizes s_ov, s_key, s_m
    if (t == 0)
      ovmaxq[bm * NQ + q] = fmaxf(fmaxf(s_m[0], s_m[1]), fmaxf(s_m[2], s_m[3]));

    // dense coalesced overlaps flush (zeros + positives)
    const f32x4* sv4 = (const f32x4*)s_ov;
    for (int idx = t; idx < KQ / 4; idx += 256)
      __builtin_nontemporal_store(sv4[idx], &ov4[idx]);

    if (wid != 0) return;         // extraction + tail: wave 0 only
    const int n = s_cnt;

    // per-quarter top-15: per-lane best over lane-strided slots
    unsigned long long bkey = 0; int bslot = -1;
    for (int e = lane; e < n; e += 64) {
      unsigned long long key = s_key[e];
      if (key > bkey) { bkey = key; bslot = e; }
    }
    int it = 0;
    for (; it < NT; ++it) {
      unsigned long long wkey = bkey;
      #pragma unroll
      for (int d = 1; d < 64; d <<= 1) {
        unsigned long long ok = __shfl_xor(wkey, d);
        if (ok > wkey) wkey = ok;
      }
      if (wkey == 0) break;       // all consumed
      if (lane == 0) ck[it] = wkey;
      if (bkey == wkey) {         // unique winner (k unique in low bits)
        s_key[bslot] = 0ULL;
        bkey = 0; bslot = -1;
        for (int e = lane; e < n; e += 64) {
          unsigned long long key = s_key[e];
          if (key > bkey) { bkey = key; bslot = e; }
        }
      }
    }
    if (lane == 0)
      for (int r = it; r < NT; ++r) ck[r] = 0ULL;
  }

  // ---- device-scope publish + last-quarter merge (wave 0 only here) ----
  __threadfence();                               // release candk/ovmaxq stores
  int lastq = 0;
  if (lane == 0) lastq = (atomicAdd(&done[bm], 1) == NQ - 1);
  lastq = __shfl(lastq, 0);
  if (!lastq) return;
  __threadfence();                               // acquire other quarters' data

  // merge 4x15 candidates -> global top-15 (value desc, idx asc), wave-wide
  unsigned long long mkey = (lane < NQ * NT)
      ? candk[(size_t)bm * NQ * NT + lane] : 0ULL;
  unsigned long long mywin = 0ULL;
  int nf = 0;
  for (int it2 = 0; it2 < NT; ++it2) {
    unsigned long long wkey = mkey;
    #pragma unroll
    for (int d = 1; d < 64; d <<= 1) {
      unsigned long long ok = __shfl_xor(wkey, d);
      if (ok > wkey) wkey = ok;
    }
    if (wkey == 0) break;
    if (lane == it2) mywin = wkey;
    if (mkey == wkey) mkey = 0ULL;               // unique winner consumed
    nf = it2 + 1;
  }
  if (lane < NT) {
    if (lane < nf) {
      const int fi = (int)(0xFFFFFFFFu - (unsigned)mywin);
      tki[bm * NT + lane] = fi;
      tkv[bm * NT + lane] = __uint_as_float((unsigned)(mywin >> 32));
      int old = atomicAdd(&fg0[(size_t)b * NK + fi], 1);
      if (old >= 1) atomicOr(flag, 1);
    } else {
      tki[bm * NT + lane] = -1;
      tkv[bm * NT + lane] = 0.f;
    }
  }
  if (lane == 0) {
    const float* om = ovmaxq + bm * NQ;
    ovmaxp[bm] = fmaxf(fmaxf(om[0], om[1]), fmaxf(om[2], om[3]));
  }
}

// ---------------------------------------------------------------------------
// kF: per (b, 256-k tile). Post-filter fg is 0/1 => unique entry per k.
// Keep-filter + rowmax + LDS slot scatter; writes dense fg + tgt (float4),
// scattered assign ones and single tso element per hit. Zeros from kAF fill.
// ---------------------------------------------------------------------------
__global__ __launch_bounds__(256) void kF(
    const float* __restrict__ gt_bboxes, const int* __restrict__ gt_labels,
    const int* __restrict__ tki, const float* __restrict__ tkv,
    const float* __restrict__ ovmaxp, const unsigned long long* __restrict__ mikey,
    const int* __restrict__ flagp, float* __restrict__ out)
{
  __shared__ int    s_tki[NM * NT];
  __shared__ float  s_tkv[NM * NT];
  __shared__ unsigned char s_keep[NM * NT];
  __shared__ float  s_rowmax[NM];
  __shared__ float  s_ovmax[NM];
  __shared__ int    s_label[NM];
  __shared__ float4 s_gtb[NM];
  __shared__ int    s_mk[256];
  __shared__ float  s_sv[256];

  const int b  = blockIdx.y;
  const int k0 = blockIdx.x * 256;
  const int t  = threadIdx.x;
  const int flag = *flagp;

  for (int e = t; e < NM * NT; e += 256) {
    s_tki[e] = tki[b * NM * NT + e];
    s_tkv[e] = tkv[b * NM * NT + e];
  }
  if (t < NM) {
    s_ovmax[t] = ovmaxp[b * NM + t];
    s_label[t] = gt_labels[b * NM + t];
    s_gtb[t] = *(const float4*)(gt_bboxes + (size_t)(b * NM + t) * 4);
  }
  s_mk[t] = -1;
  s_sv[t] = 0.f;
  __syncthreads();

  // keep flags (parallel over all 960 entries)
  for (int e = t; e < NM * NT; e += 256) {
    const int idx = s_tki[e];
    bool kp = (idx >= 0);
    if (kp && flag) {
      unsigned long long key = mikey[(size_t)b * NK + idx];
      int mi = NM - 1 - (int)(key & 0xFFFFFFFFull);   // key>0 for valid entries
      kp = (mi == e / NT);
    }
    s_keep[e] = kp;
  }
  __syncthreads();

  // post-filter row max of am over surviving entries
  if (t < NM) {
    float r = 0.f;
    for (int j = 0; j < NT; ++j) {
      const int e = t * NT + j;
      if (s_keep[e]) r = fmaxf(r, s_tkv[e]);
    }
    s_rowmax[t] = r;
  }
  __syncthreads();

  // scatter kept entries whose idx lands in this tile (unique per k);
  // write the assign ones directly (zeros from kAF fill)
  for (int e = t; e < NM * NT; e += 256) {
    if (!s_keep[e]) continue;
    const int idx = s_tki[e];
    if (idx < k0 || idx >= k0 + 256) continue;
    const int m = e / NT;
    s_mk[idx - k0] = m;
    s_sv[idx - k0] = s_tkv[e] / (s_rowmax[m] + 1e-9f) * s_ovmax[m];
    out[OUT_ASN + (size_t)(b * NM + m) * NK + idx] = 1.f;
  }
  __syncthreads();

  const int k = k0 + t;
  if (k < NK) {
    const int mk2 = s_mk[t];
    const int tb = (mk2 >= 0) ? mk2 : 0;   // argmax of all-zero column -> 0
    out[OUT_FG + (size_t)b * NK + k] = (mk2 >= 0) ? 1.f : 0.f;
    *(float4*)(out + OUT_TGT + (size_t)(b * NK + k) * 4) = s_gtb[tb];
    if (mk2 >= 0)
      out[OUT_TSO + (size_t)(b * NK + k) * NC + s_label[mk2]] = s_sv[t];
  }
}

// ---------------------------------------------------------------------------
extern "C" void kernel_launch(void* const* d_in, const int* in_sizes, int n_in,
                              void* d_out, int out_size, void* d_ws, size_t ws_size,
                              hipStream_t stream)
{
  const float* points      = (const float*)d_in[0];
  const float* gt_bboxes   = (const float*)d_in[1];
  const int*   gt_labels   = (const int*)d_in[2];
  const float* pred_bboxes = (const float*)d_in[3];
  const float* pred_scores = (const float*)d_in[4];
  const int*   gt_mask     = (const int*)d_in[5];
  float* out = (float*)d_out;

  char* ws = (char*)d_ws;
  unsigned long long* mikey = (unsigned long long*)ws; ws += (size_t)NB * NK * 8;
  int*   fg0    = (int*)ws;    ws += (size_t)NB * NK * 4;
  int*   done   = (int*)ws;    ws += (size_t)NB * NM * 4;
  int*   flag   = (int*)ws;    ws += 256;
  unsigned long long* candk = (unsigned long long*)ws;
                               ws += (size_t)NB * NM * NQ * NT * 8;
  int*   tki    = (int*)ws;    ws += (size_t)NB * NM * NT * 4;
  float* tkv    = (float*)ws;  ws += (size_t)NB * NM * NT * 4;
  float* ovmaxp = (float*)ws;  ws += (size_t)NB * NM * 4;
  float* ovmaxq = (float*)ws;  ws += (size_t)NB * NM * NQ * 4;

  // ws init (must precede kAF's mikey atomics / done counters)
  kZ<<<1024, 256, 0, stream>>>(mikey, fg0, done, flag);

  // fused fill + compute + per-bm merge tail
  kAF<<<NCOMP + NFILL, 256, 0, stream>>>(points, gt_bboxes, gt_labels,
                                         pred_bboxes, pred_scores, gt_mask,
                                         out, candk, ovmaxq, ovmaxp, tki, tkv,
                                         mikey, done, fg0, flag);

  dim3 g2((NK + 255) / 256, NB);
  kF<<<g2, 256, 0, stream>>>(gt_bboxes, gt_labels, tki, tkv, ovmaxp, mikey,
                             flag, out);
}

// Round 11
// 91.085 us; speedup vs baseline: 6.6810x; 6.6810x over previous
//
#include <hip/hip_runtime.h>
#include <math.h>

// Problem constants (match reference)
constexpr int NB = 32, NM = 64, NK = 8400, NC = 80, NT = 15;
constexpr int NQ = 4, KQ = 2100;       // k split into 4 quarters of 2100
constexpr float FEPS = 1e-7f;

typedef float f32x4 __attribute__((ext_vector_type(4)));   // NT-store compatible

// Output layout: [tso | tgt_bboxes | assign | overlaps | fg], all float32
constexpr size_t OUT_TSO = 0;
constexpr size_t OUT_TGT = (size_t)NB * NK * NC;            // 21504000
constexpr size_t OUT_ASN = OUT_TGT + (size_t)NB * NK * 4;   // 22579200
constexpr size_t OUT_OVL = OUT_ASN + (size_t)NB * NM * NK;  // 39782400
constexpr size_t OUT_FG  = OUT_OVL + (size_t)NB * NM * NK;  // 56985600

constexpr int NCOMP = NB * NM * NQ;    // 8192 compute blocks
constexpr int NFILL = 2048;            // fill blocks (every 5th block)
constexpr int N4A  = (int)(OUT_TGT / 4);              // tso region, f32x4 count
constexpr int N4B  = (int)((OUT_OVL - OUT_ASN) / 4);  // assign region
constexpr int ASN4 = (int)(OUT_ASN / 4);

// ---------------------------------------------------------------------------
// kZ: workspace init (mikey=0, fg0=0, flag=0). Must precede kAF (atomicMax).
// ---------------------------------------------------------------------------
__global__ __launch_bounds__(256) void kZ(unsigned long long* __restrict__ mikey,
                                          int* __restrict__ fg0,
                                          int* __restrict__ flag)
{
  const int n = NB * NK;
  const int tid = blockIdx.x * 256 + threadIdx.x;
  for (int i = tid; i < n; i += gridDim.x * 256) { mikey[i] = 0ULL; fg0[i] = 0; }
  if (tid == 0) *flag = 0;
}

// ---------------------------------------------------------------------------
// kAF: 10240 blocks, role-specialized (every 5th = fill, rest = compute).
// NO device fences / cross-block sync — visibility via kernel boundary.
//  fill   : streaming NT zero of tso+assign (155 MB over 2048 blocks),
//           running CONCURRENTLY with compute blocks' latency phases
//  compute: one block per (b,m,quarter):
//    pass 1: zero LDS ov tile + point-in-box -> ushort positive list
//    pass 2: CIoU on positives -> s_ov, mi atomicMax key, packed am keys
//    flush : dense f32x4 NT overlaps write from s_ov
//    tail  : per-quarter top-15 (value desc, idx asc) -> candk (wave 0)
// ---------------------------------------------------------------------------
__global__ __launch_bounds__(256) void kAF(
    const float* __restrict__ points, const float* __restrict__ gt_bboxes,
    const int* __restrict__ gt_labels, const float* __restrict__ pred_bboxes,
    const float* __restrict__ pred_scores, const int* __restrict__ gt_mask,
    float* __restrict__ out, unsigned long long* __restrict__ candk,
    float* __restrict__ ovmaxq, unsigned long long* __restrict__ mikey)
{
  __shared__ __align__(16) float s_ov[KQ];       // 8.4 KB dense overlaps tile
  __shared__ unsigned short s_pos[KQ];           // 4.2 KB positive local-idx list
  __shared__ unsigned long long s_key[KQ];       // 16.8 KB packed am candidates
  __shared__ int   s_np, s_cnt;
  __shared__ float s_m[4];

  const int bx = blockIdx.x;
  const int t  = threadIdx.x;

  // ---- fill role: every 5th block streams zeros into tso+assign ----
  if ((bx % 5) == 4) {
    const int fidx = bx / 5;
    f32x4* o4 = (f32x4*)out;
    const f32x4 z = {0.f, 0.f, 0.f, 0.f};
    for (int i = fidx * 256 + t; i < N4A + N4B; i += NFILL * 256) {
      const int a = (i < N4A) ? i : (i - N4A + ASN4);
      __builtin_nontemporal_store(z, &o4[a]);
    }
    return;
  }

  // ---- compute role ----
  const int cidx = bx - (bx + 1) / 5;            // 0..8191
  const int bm = cidx >> 2;                      // 4 quarter blocks adjacent
  const int q  = cidx & 3;
  const int b  = bm >> 6;
  const int m  = bm & 63;
  const int wid = t >> 6, lane = t & 63;
  const int kbeg = q * KQ;

  unsigned long long* ck = candk + (size_t)(bm * NQ + q) * NT;
  float* ovl_out = out + OUT_OVL + (size_t)bm * NK;
  f32x4* ov4 = (f32x4*)(ovl_out + kbeg);

  const int maskv = gt_mask[bm];
  if (!maskv) {
    const f32x4 z = {0.f, 0.f, 0.f, 0.f};
    for (int idx = t; idx < KQ / 4; idx += 256)
      __builtin_nontemporal_store(z, &ov4[idx]);
    if (t == 0) ovmaxq[bm * NQ + q] = 0.f;
    if (wid == 0 && lane < NT) ck[lane] = 0ULL;
    return;
  }
  if (t == 0) { s_np = 0; s_cnt = 0; }
  __syncthreads();

  const float4 g = *(const float4*)(gt_bboxes + (size_t)bm * 4);
  const int   label = gt_labels[bm];
  const float2* pts = (const float2*)points;

  // pass 1: zero ov tile + point-in-box (diff.max(-1)<1e-6, exact f32 subs)
  #pragma unroll
  for (int j = 0; j < 9; ++j) {
    const int idx = j * 256 + t;
    if (idx < KQ) {
      s_ov[idx] = 0.f;
      const int k = kbeg + idx;
      float2 p = pts[k];
      float dmax = fmaxf(fmaxf(g.x - p.x, g.y - p.y),
                         fmaxf(p.x - g.z, p.y - g.w));
      if (dmax < 1e-6f) {
        int e = atomicAdd(&s_np, 1);
        s_pos[e] = (unsigned short)idx;
      }
    }
  }
  __syncthreads();
  const int np = s_np;

  const float4* pb = (const float4*)(pred_bboxes + (size_t)b * NK * 4);
  const float*  ps = pred_scores + (size_t)b * NK * NC;
  unsigned long long* mk = mikey + (size_t)b * NK;

  const float w1 = g.z - g.x, h1 = g.w - g.y;
  const float at1 = atanf(w1 / (h1 + FEPS));
  const float area1 = w1 * h1;
  const float CV = (float)(4.0 / (M_PI * M_PI));
  const float ONE_EPS = (float)(1.0 + 1e-7);

  float lmax = 0.f;
  for (int e = t; e < np; e += 256) {
    const int k = kbeg + s_pos[e];
    float4 qb = pb[k];
    float w2 = qb.z - qb.x, h2 = qb.w - qb.y;
    float iw = fmaxf(fminf(g.z, qb.z) - fmaxf(g.x, qb.x), 0.f);
    float ih = fmaxf(fminf(g.w, qb.w) - fmaxf(g.y, qb.y), 0.f);
    float inter = iw * ih;
    float uni = area1 + w2 * h2 - inter + FEPS;
    float iou = inter / uni;
    float cw = fmaxf(g.z, qb.z) - fminf(g.x, qb.x);
    float ch = fmaxf(g.w, qb.w) - fminf(g.y, qb.y);
    float c2 = cw * cw + ch * ch + FEPS;
    float ex = qb.x + qb.z - g.x - g.z;
    float ey = qb.y + qb.w - g.y - g.w;
    float rho2 = (ex * ex + ey * ey) * 0.25f;
    float dat = atanf(w2 / (h2 + FEPS)) - at1;
    float v = CV * dat * dat;
    float alpha = v / (v - iou + ONE_EPS);
    float ciou = iou - (rho2 / c2 + alpha * v);
    float ov = fmaxf(ciou, 0.f);
    if (ov > 0.f) {
      s_ov[k - kbeg] = ov;
      unsigned long long key =
          ((unsigned long long)__float_as_uint(ov) << 32) |
          (unsigned long long)(NM - 1 - m);             // value desc, first-m tie
      atomicMax(&mk[k], key);
      lmax = fmaxf(lmax, ov);
      float ts = ps[(size_t)k * NC + label];
      float o2 = ov * ov;
      float am = ts * (o2 * o2 * o2);                   // ts**1 * ov**6
      if (am > 1e-9f) {                                 // below cutoff never selected
        int p2 = atomicAdd(&s_cnt, 1);
        s_key[p2] = ((unsigned long long)__float_as_uint(am) << 32) |
                    (unsigned long long)(0xFFFFFFFFu - (unsigned)k);
      }
    }
  }

  // partial row-max of overlaps
  float mv = lmax;
  #pragma unroll
  for (int d = 1; d < 64; d <<= 1) mv = fmaxf(mv, __shfl_xor(mv, d));
  if (lane == 0) s_m[wid] = mv;
  __syncthreads();   // finalizes s_ov, s_key, s_m
  if (t == 0)
    ovmaxq[bm * NQ + q] = fmaxf(fmaxf(s_m[0], s_m[1]), fmaxf(s_m[2], s_m[3]));

  // dense coalesced overlaps flush (zeros + positives)
  const f32x4* sv4 = (const f32x4*)s_ov;
  for (int idx = t; idx < KQ / 4; idx += 256)
    __builtin_nontemporal_store(sv4[idx], &ov4[idx]);

  if (wid != 0) return;         // extraction: wave 0 only
  const int n = s_cnt;

  // per-quarter top-15: per-lane best over lane-strided slots
  unsigned long long bkey = 0; int bslot = -1;
  for (int e = lane; e < n; e += 64) {
    unsigned long long key = s_key[e];
    if (key > bkey) { bkey = key; bslot = e; }
  }
  int it = 0;
  for (; it < NT; ++it) {
    unsigned long long wkey = bkey;
    #pragma unroll
    for (int d = 1; d < 64; d <<= 1) {
      unsigned long long ok = __shfl_xor(wkey, d);
      if (ok > wkey) wkey = ok;
    }
    if (wkey == 0) break;       // all consumed
    if (lane == 0) ck[it] = wkey;
    if (bkey == wkey) {         // unique winner (k unique in low bits)
      s_key[bslot] = 0ULL;
      bkey = 0; bslot = -1;
      for (int e = lane; e < n; e += 64) {
        unsigned long long key = s_key[e];
        if (key > bkey) { bkey = key; bslot = e; }
      }
    }
  }
  if (lane == 0)
    for (int r = it; r < NT; ++r) ck[r] = 0ULL;
}

// ---------------------------------------------------------------------------
// kA2: one wave per (b,m): merge 4x15 quarter candidates -> global top-15
// (identical ordering to single-pass iterative argmax), fg0/flag atomics,
// ovmax merge. Kernel boundary provides cross-XCD visibility of candk.
// ---------------------------------------------------------------------------
__global__ __launch_bounds__(64) void kA2(
    const unsigned long long* __restrict__ candk,
    const float* __restrict__ ovmaxq, float* __restrict__ ovmaxp,
    int* __restrict__ tki, float* __restrict__ tkv,
    int* __restrict__ fg0, int* __restrict__ flag)
{
  const int bm = blockIdx.x;
  const int b  = bm >> 6;
  const int lane = threadIdx.x;

  if (lane == 0) {
    const float* om = ovmaxq + bm * NQ;
    ovmaxp[bm] = fmaxf(fmaxf(om[0], om[1]), fmaxf(om[2], om[3]));
  }

  unsigned long long mkey = (lane < NQ * NT)
      ? candk[(size_t)bm * NQ * NT + lane] : 0ULL;
  unsigned long long mywin = 0ULL;
  int nf = 0;
  for (int it = 0; it < NT; ++it) {
    unsigned long long wkey = mkey;
    #pragma unroll
    for (int d = 1; d < 64; d <<= 1) {
      unsigned long long ok = __shfl_xor(wkey, d);
      if (ok > wkey) wkey = ok;
    }
    if (wkey == 0) break;
    if (lane == it) mywin = wkey;                // round-it winner kept in lane it
    if (mkey == wkey) mkey = 0ULL;               // unique winner consumed
    nf = it + 1;
  }

  if (lane < NT) {
    if (lane < nf) {
      const int fi = (int)(0xFFFFFFFFu - (unsigned)mywin);
      tki[bm * NT + lane] = fi;
      tkv[bm * NT + lane] = __uint_as_float((unsigned)(mywin >> 32));
      int old = atomicAdd(&fg0[(size_t)b * NK + fi], 1);
      if (old >= 1) atomicOr(flag, 1);
    } else {
      tki[bm * NT + lane] = -1;
      tkv[bm * NT + lane] = 0.f;
    }
  }
}

// ---------------------------------------------------------------------------
// kF: per (b, 256-k tile). Post-filter fg is 0/1 => unique entry per k.
// Keep-filter + rowmax + LDS slot scatter; writes dense fg + tgt (float4),
// scattered assign ones and single tso element per hit. Zeros from kAF fill.
// ---------------------------------------------------------------------------
__global__ __launch_bounds__(256) void kF(
    const float* __restrict__ gt_bboxes, const int* __restrict__ gt_labels,
    const int* __restrict__ tki, const float* __restrict__ tkv,
    const float* __restrict__ ovmaxp, const unsigned long long* __restrict__ mikey,
    const int* __restrict__ flagp, float* __restrict__ out)
{
  __shared__ int    s_tki[NM * NT];
  __shared__ float  s_tkv[NM * NT];
  __shared__ unsigned char s_keep[NM * NT];
  __shared__ float  s_rowmax[NM];
  __shared__ float  s_ovmax[NM];
  __shared__ int    s_label[NM];
  __shared__ float4 s_gtb[NM];
  __shared__ int    s_mk[256];
  __shared__ float  s_sv[256];

  const int b  = blockIdx.y;
  const int k0 = blockIdx.x * 256;
  const int t  = threadIdx.x;
  const int flag = *flagp;

  for (int e = t; e < NM * NT; e += 256) {
    s_tki[e] = tki[b * NM * NT + e];
    s_tkv[e] = tkv[b * NM * NT + e];
  }
  if (t < NM) {
    s_ovmax[t] = ovmaxp[b * NM + t];
    s_label[t] = gt_labels[b * NM + t];
    s_gtb[t] = *(const float4*)(gt_bboxes + (size_t)(b * NM + t) * 4);
  }
  s_mk[t] = -1;
  s_sv[t] = 0.f;
  __syncthreads();

  // keep flags (parallel over all 960 entries)
  for (int e = t; e < NM * NT; e += 256) {
    const int idx = s_tki[e];
    bool kp = (idx >= 0);
    if (kp && flag) {
      unsigned long long key = mikey[(size_t)b * NK + idx];
      int mi = NM - 1 - (int)(key & 0xFFFFFFFFull);   // key>0 for valid entries
      kp = (mi == e / NT);
    }
    s_keep[e] = kp;
  }
  __syncthreads();

  // post-filter row max of am over surviving entries
  if (t < NM) {
    float r = 0.f;
    for (int j = 0; j < NT; ++j) {
      const int e = t * NT + j;
      if (s_keep[e]) r = fmaxf(r, s_tkv[e]);
    }
    s_rowmax[t] = r;
  }
  __syncthreads();

  // scatter kept entries whose idx lands in this tile (unique per k);
  // write the assign ones directly (zeros from kAF fill)
  for (int e = t; e < NM * NT; e += 256) {
    if (!s_keep[e]) continue;
    const int idx = s_tki[e];
    if (idx < k0 || idx >= k0 + 256) continue;
    const int m = e / NT;
    s_mk[idx - k0] = m;
    s_sv[idx - k0] = s_tkv[e] / (s_rowmax[m] + 1e-9f) * s_ovmax[m];
    out[OUT_ASN + (size_t)(b * NM + m) * NK + idx] = 1.f;
  }
  __syncthreads();

  const int k = k0 + t;
  if (k < NK) {
    const int mk2 = s_mk[t];
    const int tb = (mk2 >= 0) ? mk2 : 0;   // argmax of all-zero column -> 0
    out[OUT_FG + (size_t)b * NK + k] = (mk2 >= 0) ? 1.f : 0.f;
    *(float4*)(out + OUT_TGT + (size_t)(b * NK + k) * 4) = s_gtb[tb];
    if (mk2 >= 0)
      out[OUT_TSO + (size_t)(b * NK + k) * NC + s_label[mk2]] = s_sv[t];
  }
}

// ---------------------------------------------------------------------------
extern "C" void kernel_launch(void* const* d_in, const int* in_sizes, int n_in,
                              void* d_out, int out_size, void* d_ws, size_t ws_size,
                              hipStream_t stream)
{
  const float* points      = (const float*)d_in[0];
  const float* gt_bboxes   = (const float*)d_in[1];
  const int*   gt_labels   = (const int*)d_in[2];
  const float* pred_bboxes = (const float*)d_in[3];
  const float* pred_scores = (const float*)d_in[4];
  const int*   gt_mask     = (const int*)d_in[5];
  float* out = (float*)d_out;

  char* ws = (char*)d_ws;
  unsigned long long* mikey = (unsigned long long*)ws; ws += (size_t)NB * NK * 8;
  int*   fg0    = (int*)ws;    ws += (size_t)NB * NK * 4;
  int*   flag   = (int*)ws;    ws += 256;
  unsigned long long* candk = (unsigned long long*)ws;
                               ws += (size_t)NB * NM * NQ * NT * 8;
  int*   tki    = (int*)ws;    ws += (size_t)NB * NM * NT * 4;
  float* tkv    = (float*)ws;  ws += (size_t)NB * NM * NT * 4;
  float* ovmaxp = (float*)ws;  ws += (size_t)NB * NM * 4;
  float* ovmaxq = (float*)ws;  ws += (size_t)NB * NM * NQ * 4;

  // ws init (must precede kAF's mikey atomics)
  kZ<<<1024, 256, 0, stream>>>(mikey, fg0, flag);

  // fused fill + compute (no cross-block sync inside)
  kAF<<<NCOMP + NFILL, 256, 0, stream>>>(points, gt_bboxes, gt_labels,
                                         pred_bboxes, pred_scores, gt_mask,
                                         out, candk, ovmaxq, mikey);

  kA2<<<NB * NM, 64, 0, stream>>>(candk, ovmaxq, ovmaxp, tki, tkv, fg0, flag);

  dim3 g2((NK + 255) / 256, NB);
  kF<<<g2, 256, 0, stream>>>(gt_bboxes, gt_labels, tki, tkv, ovmaxp, mikey,
                             flag, out);
}